// Round 3
// baseline (441.716 us; speedup 1.0000x reference)
//
#include <hip/hip_runtime.h>

typedef __attribute__((ext_vector_type(8))) short short8;
typedef __attribute__((ext_vector_type(4))) float f32x4;
typedef __attribute__((ext_vector_type(4))) int i32x4;
typedef __attribute__((ext_vector_type(2))) unsigned u32x2;

#define LOG2E 1.44269504f

__device__ __forceinline__ short f2bf(float f) {
  unsigned u = __builtin_bit_cast(unsigned, f);
  u += 0x7fffu + ((u >> 16) & 1u);   // round-to-nearest-even
  return (short)(u >> 16);
}

// ---------------- fused prologue ----------------
__global__ __launch_bounds__(256) void gat_pro(
    const float* __restrict__ feat, const float* __restrict__ W,
    const float* __restrict__ a1, const float* __restrict__ a2,
    short* __restrict__ featB, short* __restrict__ WB,
    float* __restrict__ AxL, float* __restrict__ AyL) {
  __shared__ __align__(16) float a1f[256], a2f[256];
  __shared__ __align__(16) float w1f[256], w2f[256];
  __shared__ __align__(16) float tile[32][260];
  const int tid = threadIdx.x;
  const int f = blockIdx.x, b = blockIdx.y;

  a1f[tid] = a1[tid];
  a2f[tid] = a2[tid];
  __syncthreads();

  {
    float s1 = 0.f, s2 = 0.f;
    const float4* wr = (const float4*)(W + (size_t)tid * 256);
    for (int d0 = 0; d0 < 64; ++d0) {
      float4 v = wr[d0];
      s1 += v.x * a1f[d0 * 4] + v.y * a1f[d0 * 4 + 1] + v.z * a1f[d0 * 4 + 2] + v.w * a1f[d0 * 4 + 3];
      s2 += v.x * a2f[d0 * 4] + v.y * a2f[d0 * 4 + 1] + v.z * a2f[d0 * 4 + 2] + v.w * a2f[d0 * 4 + 3];
    }
    w1f[tid] = s1;
    w2f[tid] = s2;
  }
  __syncthreads();

  {
    const int r = tid >> 3, g8 = tid & 7;
    const float* frow = feat + ((size_t)(b * 4096 + f * 32 + r)) * 256;
    float s1 = 0.f, s2 = 0.f;
#pragma unroll
    for (int k = 0; k < 8; ++k) {
      const int c4 = g8 + 8 * k;
      float4 v = *(const float4*)(frow + c4 * 4);
      float4 u1 = *(const float4*)&w1f[c4 * 4];
      float4 u2 = *(const float4*)&w2f[c4 * 4];
      s1 += v.x * u1.x + v.y * u1.y + v.z * u1.z + v.w * u1.w;
      s2 += v.x * u2.x + v.y * u2.y + v.z * u2.z + v.w * u2.w;
      *(float4*)&tile[r][c4 * 4] = v;
    }
#pragma unroll
    for (int off = 4; off >= 1; off >>= 1) {
      s1 += __shfl_xor(s1, off);
      s2 += __shfl_xor(s2, off);
    }
    if (g8 == 0) {
      AxL[b * 4096 + f * 32 + r] = s1 * LOG2E;
      AyL[b * 4096 + f * 32 + r] = s2 * LOG2E;
    }
  }
  __syncthreads();

  {
    const int g = tid >> 4, l15 = tid & 15;
    short* d = featB + (((size_t)((b * 128 + f) * 16 + g)) * 64) * 8;
#pragma unroll
    for (int q = 0; q < 4; ++q) {
      short8 v;
#pragma unroll
      for (int j8 = 0; j8 < 8; ++j8) v[j8] = f2bf(tile[q * 8 + j8][g * 16 + l15]);
      *(short8*)(d + (q * 16 + l15) * 8) = v;
    }
  }

  if (b == 0 && f < 8) {
    const int g = tid >> 4, l15 = tid & 15;
    const float* s = W + ((size_t)f * 32) * 256 + g * 16 + l15;
    short* d = WB + (((size_t)(f * 16 + g)) * 64) * 8;
#pragma unroll
    for (int q = 0; q < 4; ++q) {
      short8 v;
#pragma unroll
      for (int j8 = 0; j8 < 8; ++j8) v[j8] = f2bf(s[(q * 8 + j8) * 256]);
      *(short8*)(d + (q * 16 + l15) * 8) = v;
    }
  }
}

// -------- fused softmax(mask(lrelu(rank1)))@feat @W +ELU --------
// Producer/consumer wave specialization, 64-row blocks, 1 block/CU:
//   waves 0-3 (producers): adj stream + exp2 scores for 16 rows each ->
//     double-buffered Pbuf. One super-chunk ahead of consumers.
//   waves 4-7 (consumers): MFMA. Each owns 4 col-tiles (cg), processes all
//     4 row-groups -> every featB fragment loaded exactly ONCE per block.
// Waves map round-robin to SIMDs -> each SIMD hosts 1 producer + 1
// consumer; VALU/exp2/adj-stream overlaps MFMA/featB-L2 continuously
// (separate pipes), removing the phase-serialization that capped round 2.
// One barrier per super-chunk; adj prefetched one super-chunk ahead.
__global__ __launch_bounds__(512, 2) void gat_attn(
    const short* __restrict__ featB,  // [4][128][16][64][8] bf16 fragments
    const int* __restrict__ adj,      // [4][4096][4096]
    const float* __restrict__ AxL, const float* __restrict__ AyL,
    const short* __restrict__ WB,     // [8][16][64][8] bf16 fragments
    float* __restrict__ out)          // [4][4096][256] f32
{
  __shared__ short smem[33792];  // Pbuf[2][64][264]; later aliased as hbuf[64][264]
  __shared__ float mred[8];

  const int tid = threadIdx.x;
  const int blk = blockIdx.x;
  const int x = blk & 7;
  const int b = x >> 1;                       // XCD-pinned batch
  const int it = ((blk >> 3) << 1) | (x & 1); // 0..63
  const int i0 = it << 6;
  const int scoff = (blk >> 3) & 15;          // staggered j-window start

  const int lane = tid & 63;
  const int aw = tid >> 6;                    // wave 0..7
  const int l15 = lane & 15;
  const int q = lane >> 4;

  // ---- per-batch max of AxL ----
  const float* axb = AxL + b * 4096;
  float mx = -3.4e38f;
  for (int i = tid; i < 4096; i += 512) mx = fmaxf(mx, axb[i]);
#pragma unroll
  for (int off = 32; off >= 1; off >>= 1) mx = fmaxf(mx, __shfl_xor(mx, off));
  if (lane == 0) mred[aw] = mx;
  __syncthreads();
  const float MbLb = fmaxf(fmaxf(fmaxf(mred[0], mred[1]), fmaxf(mred[2], mred[3])),
                           fmaxf(fmaxf(mred[4], mred[5]), fmaxf(mred[6], mred[7])));

  const bool producer = (aw < 4);

  // ---- producer state (waves 0-3): 16 rows each ----
  const int pw = aw & 3;
  float aLk[16], ddk[16];
  const int* adjr = adj + ((size_t)(b * 4096 + i0 + pw * 16)) * 4096 + lane * 4;
  const float4* axp = (const float4*)(AxL + b * 4096) + lane;
  i32x4 adv[16];
  float4 axv;

  // ---- consumer state (waves 4-7): col-group cg (4 tiles), all 4 row-groups ----
  const int cg = (aw & 3) << 2;
  const short* fbb = featB + (size_t)b * 128 * 16 * 64 * 8 + lane * 8;
  f32x4 acc[4][4], lac[4];
#pragma unroll
  for (int r = 0; r < 4; ++r) {
    lac[r] = (f32x4){0.f, 0.f, 0.f, 0.f};
#pragma unroll
    for (int j = 0; j < 4; ++j) acc[r][j] = (f32x4){0.f, 0.f, 0.f, 0.f};
  }
  short8 ones;
#pragma unroll
  for (int j = 0; j < 8; ++j) ones[j] = (short)0x3F80;  // bf16 1.0

  if (producer) {
#pragma unroll
    for (int k = 0; k < 16; ++k) {
      float ayL = AyL[b * 4096 + i0 + pw * 16 + k];
      float sL = ayL + MbLb;
      float mrL = fmaxf(sL, 0.2f * sL);
      aLk[k] = ayL - mrL;
      ddk[k] = -0.8f * mrL;
    }
  }

  // P-compute for one window into buffer bufSel (consumes adv/axv)
  auto computeP = [&](int bufSel) {
    const float* af = (const float*)&axv;
#pragma unroll
    for (int k = 0; k < 16; ++k) {
      unsigned pr[4];
#pragma unroll
      for (int u = 0; u < 4; ++u) {
        float v = af[u] + aLk[k];
        float uu = fmaxf(v, fmaf(0.2f, v, ddk[k]));
        unsigned ub = adv[k][u] > 0 ? __builtin_bit_cast(unsigned, uu) : 0xFF800000u;
        float p = __builtin_amdgcn_exp2f(__builtin_bit_cast(float, ub));
        pr[u] = __builtin_bit_cast(unsigned, p) + 0x8000u;
      }
      u32x2 pw2;
      pw2[0] = __builtin_amdgcn_perm(pr[1], pr[0], 0x07060302u);
      pw2[1] = __builtin_amdgcn_perm(pr[3], pr[2], 0x07060302u);
      *(u32x2*)(smem + bufSel * 16896 + (pw * 16 + k) * 264 + lane * 4) = pw2;
    }
  };
  auto prefetchW = [&](int w) {
    axv = axp[w * 64];
#pragma unroll
    for (int k = 0; k < 16; ++k)
      adv[k] = __builtin_nontemporal_load((const i32x4*)(adjr) + (size_t)k * 1024 + w * 64);
  };

  // ---- pre-loop: producers build P0 and prefetch window 1 ----
  if (producer) {
    prefetchW(scoff);
    computeP(0);
    prefetchW((scoff + 1) & 15);
  }
  __syncthreads();

  // ---- main loop: one barrier per super-chunk ----
  for (int sc = 0; sc < 16; ++sc) {
    if (producer) {
      if (sc < 15) {
        computeP((sc + 1) & 1);
        if (sc < 14) prefetchW((scoff + sc + 2) & 15);
      }
    } else {
      const int wsc = (scoff + sc) & 15;
      const int pb = (sc & 1) * 16896;
#pragma unroll
      for (int h = 0; h < 8; ++h) {
        const int f = wsc * 8 + h;
        const short* fb = fbb + (((size_t)f * 16 + cg) << 9);
        short8 a[4];
#pragma unroll
        for (int r = 0; r < 4; ++r)
          a[r] = *(const short8*)(smem + pb + (r * 16 + l15) * 264 + h * 32 + q * 8);
#pragma unroll
        for (int r = 0; r < 4; ++r)
          lac[r] = __builtin_amdgcn_mfma_f32_16x16x32_bf16(a[r], ones, lac[r], 0, 0, 0);
#pragma unroll
        for (int ct = 0; ct < 4; ++ct) {
          short8 bf = *(const short8*)(fb + (ct << 9));
#pragma unroll
          for (int r = 0; r < 4; ++r)
            acc[r][ct] = __builtin_amdgcn_mfma_f32_16x16x32_bf16(a[r], bf, acc[r][ct], 0, 0, 0);
        }
      }
    }
    __syncthreads();
  }

  // ---- consumers: normalize + write h (bf16) to hbuf (aliases Pbuf) ----
  if (!producer) {
    float linv[4][4];
#pragma unroll
    for (int r = 0; r < 4; ++r)
#pragma unroll
      for (int reg = 0; reg < 4; ++reg) {
        float l = lac[r][reg];
        linv[r][reg] = l > 0.f ? 1.f / l : 0.f;
      }
    short* hbuf = smem;  // [64][264]
#pragma unroll
    for (int r = 0; r < 4; ++r)
#pragma unroll
      for (int reg = 0; reg < 4; ++reg) {
        const int lr = r * 16 + q * 4 + reg;
#pragma unroll
        for (int ct = 0; ct < 4; ++ct)
          hbuf[lr * 264 + (cg + ct) * 16 + l15] = f2bf(acc[r][ct][reg] * linv[r][reg]);
      }
  }
  __syncthreads();

  // ---- epilogue GEMM: (64x256) @ W, ELU, store; all 8 waves ----
  const int rowg = (aw & 1) << 4;    // 0/16; second group is +32
  const int cgrp = (aw >> 1) << 2;   // col-group base in 16-col units
  short* hbuf = smem;

  f32x4 ac2[2][4];
#pragma unroll
  for (int r = 0; r < 2; ++r)
#pragma unroll
    for (int j = 0; j < 4; ++j) ac2[r][j] = (f32x4){0.f, 0.f, 0.f, 0.f};

  const short* wbb = WB + lane * 8;
#pragma unroll
  for (int f = 0; f < 8; ++f) {
    short8 a0 = *(const short8*)&hbuf[(rowg + l15) * 264 + f * 32 + q * 8];
    short8 a1 = *(const short8*)&hbuf[(rowg + 32 + l15) * 264 + f * 32 + q * 8];
    const short* wb = wbb + (((size_t)f * 16 + cgrp) << 9);
#pragma unroll
    for (int ct = 0; ct < 4; ++ct) {
      short8 bf = *(const short8*)(wb + (ct << 9));
      ac2[0][ct] = __builtin_amdgcn_mfma_f32_16x16x32_bf16(a0, bf, ac2[0][ct], 0, 0, 0);
      ac2[1][ct] = __builtin_amdgcn_mfma_f32_16x16x32_bf16(a1, bf, ac2[1][ct], 0, 0, 0);
    }
  }

#pragma unroll
  for (int r = 0; r < 2; ++r)
#pragma unroll
    for (int reg = 0; reg < 4; ++reg) {
      const int row = i0 + rowg + r * 32 + q * 4 + reg;
      float* orow = out + ((size_t)(b * 4096 + row)) * 256 + cgrp * 16 + l15;
#pragma unroll
      for (int ct = 0; ct < 4; ++ct) {
        float v = ac2[r][ct][reg];
        float o = v > 0.f ? v : (__builtin_amdgcn_exp2f(v * LOG2E) - 1.f);
        __builtin_nontemporal_store(o, orow + ct * 16);
      }
    }
}

extern "C" void kernel_launch(void* const* d_in, const int* in_sizes, int n_in,
                              void* d_out, int out_size, void* d_ws, size_t ws_size,
                              hipStream_t stream) {
  (void)in_sizes; (void)n_in; (void)out_size; (void)ws_size;
  const float* feat = (const float*)d_in[0];
  const int* adj = (const int*)d_in[1];
  const float* W = (const float*)d_in[2];
  const float* a1 = (const float*)d_in[3];
  const float* a2 = (const float*)d_in[4];
  float* out = (float*)d_out;

  char* ws = (char*)d_ws;
  short* featB   = (short*)ws;                     // 4*128*16*64*8*2 = 8,388,608 B
  short* WB      = (short*)(ws + 8388608);         // 131,072 B
  float* AxL     = (float*)(ws + 8519680);         // 64 KB
  float* AyL     = (float*)(ws + 8585216);         // 64 KB

  hipLaunchKernelGGL(gat_pro, dim3(128, 4), dim3(256), 0, stream, feat, W, a1, a2, featB, WB, AxL, AyL);
  hipLaunchKernelGGL(gat_attn, dim3(256), dim3(512), 0, stream, featB, adj, AxL, AyL, WB, out);
}